// Round 5
// baseline (383.205 us; speedup 1.0000x reference)
//
#include <hip/hip_runtime.h>
#include <stdint.h>

typedef unsigned int u32;
typedef unsigned short u16;
typedef float f32x4 __attribute__((ext_vector_type(4)));
typedef __bf16 bfx8 __attribute__((ext_vector_type(8)));
typedef short s16x8 __attribute__((ext_vector_type(8)));
typedef short s16x4 __attribute__((ext_vector_type(4)));
typedef int i32x4 __attribute__((ext_vector_type(4)));

#define DEVI static __device__ __forceinline__

#if __has_builtin(__builtin_amdgcn_exp2f)
#define EXP2(x) __builtin_amdgcn_exp2f(x)
#else
#define EXP2(x) exp2f(x)
#endif

// B=4, S=1024, HIDDEN=1024, H=16, HD=64, TABLE=127

DEVI u16 f2bf(float f){
  u32 u = __builtin_bit_cast(u32, f);
  u32 r = (u + 0x7fffu + ((u >> 16) & 1u)) >> 16;  // RNE
  return (u16)r;
}
DEVI float b2f(u16 v){ return __builtin_bit_cast(float, (u32)v << 16); }
DEVI short e2s(float f){ return __builtin_bit_cast(short, (__bf16)f); }  // HW RNE cvt

struct s16x4p { s16x4 lo, hi; };
DEVI s16x8 cat4(s16x4 lo, s16x4 hi){ s16x4p p{lo, hi}; return __builtin_bit_cast(s16x8, p); }

DEVI f32x4 mfma16(s16x8 a, s16x8 b, f32x4 c){
  return __builtin_amdgcn_mfma_f32_16x16x32_bf16(
      __builtin_bit_cast(bfx8, a), __builtin_bit_cast(bfx8, b), c, 0, 0, 0);
}

DEVI void gld16(const void* g, void* l){
  __builtin_amdgcn_global_load_lds(
      (__attribute__((address_space(1))) void*)g,
      (__attribute__((address_space(3))) void*)l, 16, 0, 0);
}

// ---------------- cast kernels ----------------
__global__ void cast3_kernel(const float* __restrict__ a, const float* __restrict__ b,
                             const float* __restrict__ c, u16* __restrict__ dst){
  const long n_each = 4194304;  // 4*1024*1024
  long stride = (long)gridDim.x * blockDim.x;
  for (long v = (long)blockIdx.x * blockDim.x + threadIdx.x; v < 3 * n_each / 8; v += stride){
    long idx8 = v * 8;
    int which = (int)(idx8 / n_each);
    long off = idx8 - (long)which * n_each;
    const float* s = which == 0 ? a : (which == 1 ? b : c);
    float4 f0 = *(const float4*)(s + off);
    float4 f1 = *(const float4*)(s + off + 4);
    s16x8 o;
    o[0]=(short)f2bf(f0.x); o[1]=(short)f2bf(f0.y); o[2]=(short)f2bf(f0.z); o[3]=(short)f2bf(f0.w);
    o[4]=(short)f2bf(f1.x); o[5]=(short)f2bf(f1.y); o[6]=(short)f2bf(f1.z); o[7]=(short)f2bf(f1.w);
    *(s16x8*)(dst + idx8) = o;
  }
}

__global__ void cast1_kernel(const float* __restrict__ a, u16* __restrict__ dst, long n){
  long stride = (long)gridDim.x * blockDim.x;
  for (long v = (long)blockIdx.x * blockDim.x + threadIdx.x; v < n / 8; v += stride){
    long idx8 = v * 8;
    float4 f0 = *(const float4*)(a + idx8);
    float4 f1 = *(const float4*)(a + idx8 + 4);
    s16x8 o;
    o[0]=(short)f2bf(f0.x); o[1]=(short)f2bf(f0.y); o[2]=(short)f2bf(f0.z); o[3]=(short)f2bf(f0.w);
    o[4]=(short)f2bf(f1.x); o[5]=(short)f2bf(f1.y); o[6]=(short)f2bf(f1.z); o[7]=(short)f2bf(f1.w);
    *(s16x8*)(dst + idx8) = o;
  }
}

// Wq/Wk/Wv [H][1024][64] fp32 -> Wt [3*1024][1024] bf16  (row n = proj*1024+h*64+d)
__global__ void wtrans_kernel(const float* __restrict__ Wq, const float* __restrict__ Wk,
                              const float* __restrict__ Wv, u16* __restrict__ Wt){
  int bid = blockIdx.x;                 // 3*16*16 = 768
  int kt = bid & 15; int h = (bid >> 4) & 15; int proj = bid >> 8;
  const float* W = (proj == 0 ? Wq : (proj == 1 ? Wk : Wv)) + (long)h * (1024 * 64);
  __shared__ u16 lt[64][66];
  int t = threadIdx.x;
  #pragma unroll
  for (int it = 0; it < 16; ++it){
    int idx = it * 256 + t;
    int r = idx >> 6, d = idx & 63;
    lt[r][d] = f2bf(W[(long)(kt * 64 + r) * 64 + d]);
  }
  __syncthreads();
  long outbase = (long)proj * 1024 + h * 64;
  #pragma unroll
  for (int it = 0; it < 16; ++it){
    int idx = it * 256 + t;
    int d = idx >> 6, r = idx & 63;
    Wt[(outbase + d) * 1024 + kt * 64 + r] = lt[r][d];
  }
}

// rp_k [127][64] -> rpkb [128][64] bf16 (row 127 zero)
// rp_v [127][64] -> rpvT [64][128] bf16 (col 127 zero)
__global__ void tables_kernel(const float* __restrict__ rpk, const float* __restrict__ rpv,
                              u16* __restrict__ rpkb, u16* __restrict__ rpvT){
  int t = threadIdx.x;
  for (int i = t; i < 128 * 64; i += 256){
    int row = i >> 6, d = i & 63;
    rpkb[i] = (row < 127) ? f2bf(rpk[row * 64 + d]) : (u16)0;
  }
  for (int i = t; i < 64 * 128; i += 256){
    int d = i >> 7, row = i & 127;
    rpvT[i] = (row < 127) ? f2bf(rpv[row * 64 + d]) : (u16)0;
  }
}

// Vb [64bh][1024 s][64 d] -> Vt [64bh][64 d][1024 s]
__global__ void vtrans_kernel(const u16* __restrict__ Vb, u16* __restrict__ Vt){
  int bid = blockIdx.x;                 // 64*16 = 1024
  int st = bid & 15, bh = bid >> 4;
  const u16* src = Vb + ((long)bh * 1024 + st * 64) * 64;
  u16* dst = Vt + (long)bh * 64 * 1024 + st * 64;
  __shared__ u16 lt[64][66];
  int t = threadIdx.x;
  #pragma unroll
  for (int it = 0; it < 16; ++it){
    int idx = it * 256 + t;
    int r = idx >> 6, d = idx & 63;
    lt[r][d] = src[idx];
  }
  __syncthreads();
  #pragma unroll
  for (int it = 0; it < 16; ++it){
    int idx = it * 256 + t;
    int d = idx >> 6, r = idx & 63;
    dst[(long)d * 1024 + r] = lt[r][d];
  }
}

// ---------------- shared GEMM core: 128x128 tile, BK=64, K=1024 ----------------
DEVI void gemm_core(const u16* __restrict__ A, const u16* __restrict__ Bt,
                    int m0, int n0, u16* lds, int tid, f32x4 (&acc)[4][4]){
  const int K = 1024;
  int w = tid >> 6, lane = tid & 63, g = lane >> 4, li = lane & 15;
  int wm = w >> 1, wn = w & 1;
  for (int ks = 0; ks < 16; ++ks){
    int k0 = ks * 64;
    __syncthreads();
    #pragma unroll
    for (int i = 0; i < 4; ++i){
      int c = i * 256 + w * 64 + lane;
      int r = c >> 3, s = lane & 7;
      int kk = k0 + ((s ^ (r & 7)) << 3);   // pre-swizzled global source
      gld16(A + (long)(m0 + r) * K + kk, (char*)lds + (i * 256 + w * 64) * 16);
      gld16(Bt + (long)(n0 + r) * K + kk, (char*)lds + 16384 + (i * 256 + w * 64) * 16);
    }
    __syncthreads();
    #pragma unroll
    for (int kh = 0; kh < 2; ++kh){
      s16x8 af[4], bfr[4];
      #pragma unroll
      for (int mi = 0; mi < 4; ++mi){
        int row = wm * 64 + mi * 16 + li;
        int byt = (row * 128 + (kh * 32 + g * 8) * 2) ^ ((li & 7) << 4);
        af[mi] = *(const s16x8*)((const char*)lds + byt);
      }
      #pragma unroll
      for (int ni = 0; ni < 4; ++ni){
        int row = wn * 64 + ni * 16 + li;
        int byt = 16384 + ((row * 128 + (kh * 32 + g * 8) * 2) ^ ((li & 7) << 4));
        bfr[ni] = *(const s16x8*)((const char*)lds + byt);
      }
      #pragma unroll
      for (int mi = 0; mi < 4; ++mi)
        #pragma unroll
        for (int ni = 0; ni < 4; ++ni)
          acc[mi][ni] = mfma16(af[mi], bfr[ni], acc[mi][ni]);
    }
  }
}

// QKV projection: M=4096 tokens, N=3072 (proj*1024 + h*64 + d)
__launch_bounds__(256, 2)
__global__ void gemm_qkv(const u16* __restrict__ Xb, const u16* __restrict__ Wt,
                         const float* __restrict__ bq, const float* __restrict__ bk,
                         const float* __restrict__ bv,
                         u16* __restrict__ Qb, u16* __restrict__ Kb, u16* __restrict__ Vb){
  __shared__ __align__(16) u16 lds[16384];
  int tid = threadIdx.x;
  int bo = blockIdx.x;                   // 768 = 8 * 96 -> XCD-aware swizzle
  int bidx = (bo & 7) * 96 + (bo >> 3);
  int bn = bidx % 24, bm = bidx / 24;
  int m0 = bm * 128, n0 = bn * 128;
  int proj = n0 >> 10;
  const u16* A = Xb + (long)proj * 4096 * 1024;
  f32x4 acc[4][4] = {};
  gemm_core(A, Wt, m0, n0, lds, tid, acc);
  int w = tid >> 6, lane = tid & 63, g = lane >> 4, li = lane & 15;
  int wm = w >> 1, wn = w & 1;
  const float* bias = proj == 0 ? bq : (proj == 1 ? bk : bv);
  u16* Dst = proj == 0 ? Qb : (proj == 1 ? Kb : Vb);
  // Q gets 1/sqrt(64) * log2(e) folded in (attention uses exp2)
  float scale = (proj == 0) ? 0.125f * 1.44269504f : 1.0f;
  #pragma unroll
  for (int mi = 0; mi < 4; ++mi)
    #pragma unroll
    for (int ni = 0; ni < 4; ++ni)
      #pragma unroll
      for (int r = 0; r < 4; ++r){
        int m = m0 + wm * 64 + mi * 16 + g * 4 + r;
        int n = n0 + wn * 64 + ni * 16 + li;
        int nn = n & 1023;
        float v = (acc[mi][ni][r] + bias[nn]) * scale;
        int b = m >> 10, s = m & 1023;
        int h = nn >> 6, d = nn & 63;
        Dst[((long)(b * 16 + h) * 1024 + s) * 64 + d] = f2bf(v);
      }
}

// FC: M=4096, N=1024, fp32 out + bfc
__launch_bounds__(256, 2)
__global__ void gemm_fc(const u16* __restrict__ Hid, const u16* __restrict__ Wfcb,
                        const float* __restrict__ bfc, float* __restrict__ out){
  __shared__ __align__(16) u16 lds[16384];
  int tid = threadIdx.x;
  int bidx = blockIdx.x;                 // 32*8 = 256
  int bn = bidx & 7, bm = bidx >> 3;
  int m0 = bm * 128, n0 = bn * 128;
  f32x4 acc[4][4] = {};
  gemm_core(Hid, Wfcb, m0, n0, lds, tid, acc);
  int w = tid >> 6, lane = tid & 63, g = lane >> 4, li = lane & 15;
  int wm = w >> 1, wn = w & 1;
  #pragma unroll
  for (int mi = 0; mi < 4; ++mi)
    #pragma unroll
    for (int ni = 0; ni < 4; ++ni)
      #pragma unroll
      for (int r = 0; r < 4; ++r){
        int m = m0 + wm * 64 + mi * 16 + g * 4 + r;
        int n = n0 + wn * 64 + ni * 16 + li;
        out[(long)m * 1024 + n] = acc[mi][ni][r] + bfc[n];
      }
}

// ---------------- fused rel-pos attention (v2: wave-independent i-split) ----------------
// grid (16 i-tiles, 64 bh), 256 threads. Q pre-scaled by log2e/8; exp2 domain.
// Wave w owns i-rows [i0+16w, i0+16w+16) x ALL 1024 j. No cross-wave sharing:
// rq table, band-weight buffer, band GEMM, reductions all wave-private ->
// ZERO __syncthreads. Per-wave regs ~110 (oacc 16 f32) -> 4 blocks/CU vs r4's 2.
// r4 lesson: VGPR_Count excludes AGPRs; j-split's oacc[4][4] (64 AGPR) +
// barriers pinned residency at 2 blocks/CU and 75us regardless of prefetch.
__launch_bounds__(256, 2)
__global__ void attn_kernel(const u16* __restrict__ Qb, const u16* __restrict__ Kb,
                            const u16* __restrict__ Vt, const u16* __restrict__ rpkb,
                            const u16* __restrict__ rpvT, u16* __restrict__ Hid){
  const int S = 1024;
  int bh = blockIdx.y;
  int i0 = blockIdx.x * 64;
  int bb = bh >> 4, hh = bh & 15;
  const u16* Qp = Qb + (long)bh * S * 64;
  const u16* Kp = Kb + (long)bh * S * 64;
  const u16* Vp = Vt + (long)bh * 64 * S;
  int tid = threadIdx.x, w = tid >> 6, lane = tid & 63, g = lane >> 4, li = lane & 15;
  int gi0 = i0 + w * 16;               // wave's global i-base

  __shared__ __align__(16) u16 rqb[64 * 128];  // [64][128] rq table, rows 16w..16w+16 wave-private
  __shared__ __align__(16) u16 bwb[64 * 128];  // [64][128] band weights, XOR-swizzled, wave-private rows

  // Q fragments for this wave's 16 rows: A/B dual-use, row/col = li, k = kh*32+g*8
  s16x8 qf[2];
  #pragma unroll
  for (int kh = 0; kh < 2; ++kh)
    qf[kh] = *(const s16x8*)(Qp + (long)(gi0 + li) * 64 + kh * 32 + g * 8);

  { // zero this wave's 16 bw rows (4KB)
    i32x4 z = {0, 0, 0, 0};
    i32x4* bz = (i32x4*)(bwb + w * 16 * 128);
    #pragma unroll
    for (int zz = 0; zz < 4; ++zz) bz[zz * 64 + lane] = z;
  }

  // rq[i][t] = Q[i]·rp_k[t] for wave's rows: 8 t-blocks x 2 MFMA.
  // A=qf (m=i_local), B=pf (n=t_local); D rows on (g,e), cols on li.
  #pragma unroll
  for (int tb = 0; tb < 8; ++tb){
    s16x8 pf0 = *(const s16x8*)(rpkb + (tb * 16 + li) * 64 + g * 8);
    s16x8 pf1 = *(const s16x8*)(rpkb + (tb * 16 + li) * 64 + 32 + g * 8);
    f32x4 r = {0.f, 0.f, 0.f, 0.f};
    r = mfma16(qf[0], pf0, r);
    r = mfma16(qf[1], pf1, r);
    #pragma unroll
    for (int e = 0; e < 4; ++e)
      rqb[(w * 16 + g * 4 + e) * 128 + tb * 16 + li] = f2bf(r[e]);
  }

  // edge rq values (t=0 / t=126) in registers, indexed i=li
  float rqL = b2f(rqb[(w * 16 + li) * 128]);
  float rqR = b2f(rqb[(w * 16 + li) * 128 + 126]);

  f32x4 oacc[4] = {};                  // O[i on (g,r)][d = nd*16+li]
  float dacc = 0.f, Lac = 0.f, Rac = 0.f;   // per-lane, i = li

  for (int js = 0; js < 64; js += 2){
    int jb = js * 16;                  // 32 j per iteration (one PV K-step)
    s16x8 kf[2][2];
    #pragma unroll
    for (int p = 0; p < 2; ++p)
      #pragma unroll
      for (int kh = 0; kh < 2; ++kh)
        kf[p][kh] = *(const s16x8*)(Kp + (long)(jb + p * 16 + li) * 64 + kh * 32 + g * 8);
    s16x8 vv[4];
    #pragma unroll
    for (int nd = 0; nd < 4; ++nd){
      const u16* vp = Vp + (long)(nd * 16 + li) * S + jb + g * 4;
      vv[nd] = cat4(*(const s16x4*)(vp), *(const s16x4*)(vp + 16));
    }
    s16x8 av;
    #pragma unroll
    for (int p = 0; p < 2; ++p){
      int js0 = jb + p * 16;
      f32x4 sacc = {0.f, 0.f, 0.f, 0.f};
      sacc = mfma16(kf[p][0], qf[0], sacc);   // S^T: j on (g,r), i on li
      sacc = mfma16(kf[p][1], qf[1], sacc);
      if (js0 >= gi0 + 78){
        // whole subtile right-clipped (t=126)
        #pragma unroll
        for (int r = 0; r < 4; ++r){
          float e = EXP2(sacc[r] + rqR);
          Rac += e;
          av[p * 4 + r] = e2s(e);
        }
      } else if (js0 + 78 <= gi0){
        // whole subtile left-clipped (t=0)
        #pragma unroll
        for (int r = 0; r < 4; ++r){
          float e = EXP2(sacc[r] + rqL);
          Lac += e;
          av[p * 4 + r] = e2s(e);
        }
      } else {
        // mixed subtile: clamped rq gather (bank-spread), in-band bw write
        #pragma unroll
        for (int r = 0; r < 4; ++r){
          int jgl = js0 + g * 4 + r;
          int delta = jgl - (gi0 + li);
          int dcl = delta < -62 ? -62 : (delta > 62 ? 62 : delta);
          int tg = dcl + 63;                  // in [1,125]
          float rqv = b2f(rqb[(w * 16 + li) * 128 + tg]);
          bool lft = delta < -62, rgt = delta > 62;
          rqv = lft ? rqL : (rgt ? rqR : rqv);
          float e = EXP2(sacc[r] + rqv);
          short eb = e2s(e);
          av[p * 4 + r] = eb;
          if (!lft && !rgt){
            int byt = ((w * 16 + li) * 256 + tg * 2) ^ ((li & 7) << 4);
            *(u16*)((char*)bwb + byt) = (u16)eb;
            dacc += e;
          }
          Lac += lft ? e : 0.f;
          Rac += rgt ? e : 0.f;
        }
      }
    }
    // PV: A=av (m=i on li, k-slots j), B=vv (same permuted k-map) -> D rows i on (g,r)
    #pragma unroll
    for (int nd = 0; nd < 4; ++nd)
      oacc[nd] = mfma16(av, vv[nd], oacc[nd]);
  }

  // intra-wave reductions over g (i = li per lane)
  dacc += __shfl_xor(dacc, 16); dacc += __shfl_xor(dacc, 32);
  Lac  += __shfl_xor(Lac, 16);  Lac  += __shfl_xor(Lac, 32);
  Rac  += __shfl_xor(Rac, 16);  Rac  += __shfl_xor(Rac, 32);
  float Dtot = dacc + Lac + Rac;
  // clipped-tail weights into bw cols t=0 / t=126 (rows w*16+li)
  if (g == 0){
    *(u16*)((char*)bwb + (((w * 16 + li) * 256 + 0)   ^ ((li & 7) << 4))) = f2bf(Lac);
    *(u16*)((char*)bwb + (((w * 16 + li) * 256 + 252) ^ ((li & 7) << 4))) = f2bf(Rac);
  }
  // band GEMM: bias[i][d] = bw_rows @ rpvT^T (canonical k-map both sides)
  f32x4 bacc[4] = {};
  #pragma unroll
  for (int ksl = 0; ksl < 4; ++ksl){
    int byt = (((w * 16 + li) * 256) + (ksl * 32 + g * 8) * 2) ^ ((li & 7) << 4);
    s16x8 a = *(const s16x8*)((const char*)bwb + byt);
    #pragma unroll
    for (int nd = 0; nd < 4; ++nd){
      s16x8 rv = *(const s16x8*)(rpvT + (nd * 16 + li) * 128 + ksl * 32 + g * 8);
      bacc[nd] = mfma16(a, rv, bacc[nd]);
    }
  }
  // denominators for output rows i = g*4+r (bpermute from lane li=g*4+r)
  float inv[4];
  #pragma unroll
  for (int r = 0; r < 4; ++r)
    inv[r] = 1.0f / __shfl(Dtot, g * 4 + r);
  // write hidden[b][s=i][h*64+d], i = gi0 + g*4 + r, d = nd*16 + li
  #pragma unroll
  for (int nd = 0; nd < 4; ++nd)
    #pragma unroll
    for (int r = 0; r < 4; ++r){
      float o = (oacc[nd][r] + bacc[nd][r]) * inv[r];
      Hid[((long)bb * S + gi0 + g * 4 + r) * 1024 + hh * 64 + nd * 16 + li] = f2bf(o);
    }
}

// ---------------- launch ----------------
extern "C" void kernel_launch(void* const* d_in, const int* in_sizes, int n_in,
                              void* d_out, int out_size, void* d_ws, size_t ws_size,
                              hipStream_t stream){
  const float* query = (const float*)d_in[0];
  const float* key   = (const float*)d_in[1];
  const float* value = (const float*)d_in[2];
  const float* Wq  = (const float*)d_in[3];
  const float* Wk  = (const float*)d_in[4];
  const float* Wv  = (const float*)d_in[5];
  const float* bq  = (const float*)d_in[6];
  const float* bk  = (const float*)d_in[7];
  const float* bv  = (const float*)d_in[8];
  const float* rpk = (const float*)d_in[9];
  const float* rpv = (const float*)d_in[10];
  const float* Wfc = (const float*)d_in[11];
  const float* bfc = (const float*)d_in[12];
  float* out = (float*)d_out;

  u16* Xb   = (u16*)d_ws;                  // [3][4096][1024]
  u16* Wt   = Xb + 3L * 4096 * 1024;       // [3072][1024]
  u16* Wfcb = Wt + 3072L * 1024;           // [1024][1024]
  u16* rpkb = Wfcb + 1024L * 1024;         // [128][64]
  u16* rpvT = rpkb + 128 * 64;             // [64][128]
  u16* Qb   = rpvT + 64 * 128;             // [64][1024][64]
  u16* Kb   = Qb + 64L * 1024 * 64;
  u16* Vb   = Kb + 64L * 1024 * 64;
  u16* Vt   = Vb + 64L * 1024 * 64;        // [64][64][1024]
  u16* Hid  = Vt + 64L * 1024 * 64;        // [4096][1024]

  cast3_kernel<<<2048, 256, 0, stream>>>(query, key, value, Xb);
  cast1_kernel<<<512, 256, 0, stream>>>(Wfc, Wfcb, 1024L * 1024);
  wtrans_kernel<<<768, 256, 0, stream>>>(Wq, Wk, Wv, Wt);
  tables_kernel<<<1, 256, 0, stream>>>(rpk, rpv, rpkb, rpvT);
  gemm_qkv<<<768, 256, 0, stream>>>(Xb, Wt, bq, bk, bv, Qb, Kb, Vb);
  vtrans_kernel<<<1024, 256, 0, stream>>>(Vb, Vt);
  attn_kernel<<<dim3(16, 64), 256, 0, stream>>>(Qb, Kb, Vt, rpkb, rpvT, Hid);
  gemm_fc<<<256, 256, 0, stream>>>(Hid, Wfcb, bfc, out);
}

// Round 8
// 258.276 us; speedup vs baseline: 1.4837x; 1.4837x over previous
//
#include <hip/hip_runtime.h>
#include <stdint.h>

typedef unsigned int u32;
typedef unsigned short u16;
typedef float f32x4 __attribute__((ext_vector_type(4)));
typedef __bf16 bfx8 __attribute__((ext_vector_type(8)));
typedef short s16x8 __attribute__((ext_vector_type(8)));
typedef short s16x4 __attribute__((ext_vector_type(4)));
typedef int i32x4 __attribute__((ext_vector_type(4)));

#define DEVI static __device__ __forceinline__

#if __has_builtin(__builtin_amdgcn_exp2f)
#define EXP2(x) __builtin_amdgcn_exp2f(x)
#else
#define EXP2(x) exp2f(x)
#endif

// B=4, S=1024, HIDDEN=1024, H=16, HD=64, TABLE=127

DEVI u16 f2bf(float f){
  u32 u = __builtin_bit_cast(u32, f);
  u32 r = (u + 0x7fffu + ((u >> 16) & 1u)) >> 16;  // RNE
  return (u16)r;
}
DEVI float b2f(u16 v){ return __builtin_bit_cast(float, (u32)v << 16); }
DEVI short e2s(float f){ return __builtin_bit_cast(short, (__bf16)f); }  // HW RNE cvt

struct s16x4p { s16x4 lo, hi; };
DEVI s16x8 cat4(s16x4 lo, s16x4 hi){ s16x4p p{lo, hi}; return __builtin_bit_cast(s16x8, p); }

DEVI f32x4 mfma16(s16x8 a, s16x8 b, f32x4 c){
  return __builtin_amdgcn_mfma_f32_16x16x32_bf16(
      __builtin_bit_cast(bfx8, a), __builtin_bit_cast(bfx8, b), c, 0, 0, 0);
}

DEVI void gld16(const void* g, void* l){
  __builtin_amdgcn_global_load_lds(
      (__attribute__((address_space(1))) void*)g,
      (__attribute__((address_space(3))) void*)l, 16, 0, 0);
}

// ---------------- cast kernels ----------------
__global__ void cast3_kernel(const float* __restrict__ a, const float* __restrict__ b,
                             const float* __restrict__ c, u16* __restrict__ dst){
  const long n_each = 4194304;  // 4*1024*1024
  long stride = (long)gridDim.x * blockDim.x;
  for (long v = (long)blockIdx.x * blockDim.x + threadIdx.x; v < 3 * n_each / 8; v += stride){
    long idx8 = v * 8;
    int which = (int)(idx8 / n_each);
    long off = idx8 - (long)which * n_each;
    const float* s = which == 0 ? a : (which == 1 ? b : c);
    float4 f0 = *(const float4*)(s + off);
    float4 f1 = *(const float4*)(s + off + 4);
    s16x8 o;
    o[0]=(short)f2bf(f0.x); o[1]=(short)f2bf(f0.y); o[2]=(short)f2bf(f0.z); o[3]=(short)f2bf(f0.w);
    o[4]=(short)f2bf(f1.x); o[5]=(short)f2bf(f1.y); o[6]=(short)f2bf(f1.z); o[7]=(short)f2bf(f1.w);
    *(s16x8*)(dst + idx8) = o;
  }
}

__global__ void cast1_kernel(const float* __restrict__ a, u16* __restrict__ dst, long n){
  long stride = (long)gridDim.x * blockDim.x;
  for (long v = (long)blockIdx.x * blockDim.x + threadIdx.x; v < n / 8; v += stride){
    long idx8 = v * 8;
    float4 f0 = *(const float4*)(a + idx8);
    float4 f1 = *(const float4*)(a + idx8 + 4);
    s16x8 o;
    o[0]=(short)f2bf(f0.x); o[1]=(short)f2bf(f0.y); o[2]=(short)f2bf(f0.z); o[3]=(short)f2bf(f0.w);
    o[4]=(short)f2bf(f1.x); o[5]=(short)f2bf(f1.y); o[6]=(short)f2bf(f1.z); o[7]=(short)f2bf(f1.w);
    *(s16x8*)(dst + idx8) = o;
  }
}

// Wq/Wk/Wv [H][1024][64] fp32 -> Wt [3*1024][1024] bf16  (row n = proj*1024+h*64+d)
__global__ void wtrans_kernel(const float* __restrict__ Wq, const float* __restrict__ Wk,
                              const float* __restrict__ Wv, u16* __restrict__ Wt){
  int bid = blockIdx.x;                 // 3*16*16 = 768
  int kt = bid & 15; int h = (bid >> 4) & 15; int proj = bid >> 8;
  const float* W = (proj == 0 ? Wq : (proj == 1 ? Wk : Wv)) + (long)h * (1024 * 64);
  __shared__ u16 lt[64][66];
  int t = threadIdx.x;
  #pragma unroll
  for (int it = 0; it < 16; ++it){
    int idx = it * 256 + t;
    int r = idx >> 6, d = idx & 63;
    lt[r][d] = f2bf(W[(long)(kt * 64 + r) * 64 + d]);
  }
  __syncthreads();
  long outbase = (long)proj * 1024 + h * 64;
  #pragma unroll
  for (int it = 0; it < 16; ++it){
    int idx = it * 256 + t;
    int d = idx >> 6, r = idx & 63;
    Wt[(outbase + d) * 1024 + kt * 64 + r] = lt[r][d];
  }
}

// rp_k [127][64] -> rpkb [128][64] bf16 (row 127 zero)
// rp_v [127][64] -> rpvT [64][128] bf16 (col 127 zero)
__global__ void tables_kernel(const float* __restrict__ rpk, const float* __restrict__ rpv,
                              u16* __restrict__ rpkb, u16* __restrict__ rpvT){
  int t = threadIdx.x;
  for (int i = t; i < 128 * 64; i += 256){
    int row = i >> 6, d = i & 63;
    rpkb[i] = (row < 127) ? f2bf(rpk[row * 64 + d]) : (u16)0;
  }
  for (int i = t; i < 64 * 128; i += 256){
    int d = i >> 7, row = i & 127;
    rpvT[i] = (row < 127) ? f2bf(rpv[row * 64 + d]) : (u16)0;
  }
}

// Vb [64bh][1024 s][64 d] -> Vt [64bh][64 d][1024 s]
__global__ void vtrans_kernel(const u16* __restrict__ Vb, u16* __restrict__ Vt){
  int bid = blockIdx.x;                 // 64*16 = 1024
  int st = bid & 15, bh = bid >> 4;
  const u16* src = Vb + ((long)bh * 1024 + st * 64) * 64;
  u16* dst = Vt + (long)bh * 64 * 1024 + st * 64;
  __shared__ u16 lt[64][66];
  int t = threadIdx.x;
  #pragma unroll
  for (int it = 0; it < 16; ++it){
    int idx = it * 256 + t;
    int r = idx >> 6, d = idx & 63;
    lt[r][d] = src[idx];
  }
  __syncthreads();
  #pragma unroll
  for (int it = 0; it < 16; ++it){
    int idx = it * 256 + t;
    int d = idx >> 6, r = idx & 63;
    dst[(long)d * 1024 + r] = lt[r][d];
  }
}

// ---------------- shared GEMM core: 128x128 tile, BK=64, K=1024 ----------------
DEVI void gemm_core(const u16* __restrict__ A, const u16* __restrict__ Bt,
                    int m0, int n0, u16* lds, int tid, f32x4 (&acc)[4][4]){
  const int K = 1024;
  int w = tid >> 6, lane = tid & 63, g = lane >> 4, li = lane & 15;
  int wm = w >> 1, wn = w & 1;
  for (int ks = 0; ks < 16; ++ks){
    int k0 = ks * 64;
    __syncthreads();
    #pragma unroll
    for (int i = 0; i < 4; ++i){
      int c = i * 256 + w * 64 + lane;
      int r = c >> 3, s = lane & 7;
      int kk = k0 + ((s ^ (r & 7)) << 3);   // pre-swizzled global source
      gld16(A + (long)(m0 + r) * K + kk, (char*)lds + (i * 256 + w * 64) * 16);
      gld16(Bt + (long)(n0 + r) * K + kk, (char*)lds + 16384 + (i * 256 + w * 64) * 16);
    }
    __syncthreads();
    #pragma unroll
    for (int kh = 0; kh < 2; ++kh){
      s16x8 af[4], bfr[4];
      #pragma unroll
      for (int mi = 0; mi < 4; ++mi){
        int row = wm * 64 + mi * 16 + li;
        int byt = (row * 128 + (kh * 32 + g * 8) * 2) ^ ((li & 7) << 4);
        af[mi] = *(const s16x8*)((const char*)lds + byt);
      }
      #pragma unroll
      for (int ni = 0; ni < 4; ++ni){
        int row = wn * 64 + ni * 16 + li;
        int byt = 16384 + ((row * 128 + (kh * 32 + g * 8) * 2) ^ ((li & 7) << 4));
        bfr[ni] = *(const s16x8*)((const char*)lds + byt);
      }
      #pragma unroll
      for (int mi = 0; mi < 4; ++mi)
        #pragma unroll
        for (int ni = 0; ni < 4; ++ni)
          acc[mi][ni] = mfma16(af[mi], bfr[ni], acc[mi][ni]);
    }
  }
}

// QKV projection: M=4096 tokens, N=3072 (proj*1024 + h*64 + d)
__launch_bounds__(256, 2)
__global__ void gemm_qkv(const u16* __restrict__ Xb, const u16* __restrict__ Wt,
                         const float* __restrict__ bq, const float* __restrict__ bk,
                         const float* __restrict__ bv,
                         u16* __restrict__ Qb, u16* __restrict__ Kb, u16* __restrict__ Vb){
  __shared__ __align__(16) u16 lds[16384];
  int tid = threadIdx.x;
  int bo = blockIdx.x;                   // 768 = 8 * 96 -> XCD-aware swizzle
  int bidx = (bo & 7) * 96 + (bo >> 3);
  int bn = bidx % 24, bm = bidx / 24;
  int m0 = bm * 128, n0 = bn * 128;
  int proj = n0 >> 10;
  const u16* A = Xb + (long)proj * 4096 * 1024;
  f32x4 acc[4][4] = {};
  gemm_core(A, Wt, m0, n0, lds, tid, acc);
  int w = tid >> 6, lane = tid & 63, g = lane >> 4, li = lane & 15;
  int wm = w >> 1, wn = w & 1;
  const float* bias = proj == 0 ? bq : (proj == 1 ? bk : bv);
  u16* Dst = proj == 0 ? Qb : (proj == 1 ? Kb : Vb);
  // Q gets 1/sqrt(64) * log2(e) folded in (attention uses exp2)
  float scale = (proj == 0) ? 0.125f * 1.44269504f : 1.0f;
  #pragma unroll
  for (int mi = 0; mi < 4; ++mi)
    #pragma unroll
    for (int ni = 0; ni < 4; ++ni)
      #pragma unroll
      for (int r = 0; r < 4; ++r){
        int m = m0 + wm * 64 + mi * 16 + g * 4 + r;
        int n = n0 + wn * 64 + ni * 16 + li;
        int nn = n & 1023;
        float v = (acc[mi][ni][r] + bias[nn]) * scale;
        int b = m >> 10, s = m & 1023;
        int h = nn >> 6, d = nn & 63;
        Dst[((long)(b * 16 + h) * 1024 + s) * 64 + d] = f2bf(v);
      }
}

// FC: M=4096, N=1024, fp32 out + bfc
__launch_bounds__(256, 2)
__global__ void gemm_fc(const u16* __restrict__ Hid, const u16* __restrict__ Wfcb,
                        const float* __restrict__ bfc, float* __restrict__ out){
  __shared__ __align__(16) u16 lds[16384];
  int tid = threadIdx.x;
  int bidx = blockIdx.x;                 // 32*8 = 256
  int bn = bidx & 7, bm = bidx >> 3;
  int m0 = bm * 128, n0 = bn * 128;
  f32x4 acc[4][4] = {};
  gemm_core(Hid, Wfcb, m0, n0, lds, tid, acc);
  int w = tid >> 6, lane = tid & 63, g = lane >> 4, li = lane & 15;
  int wm = w >> 1, wn = w & 1;
  #pragma unroll
  for (int mi = 0; mi < 4; ++mi)
    #pragma unroll
    for (int ni = 0; ni < 4; ++ni)
      #pragma unroll
      for (int r = 0; r < 4; ++r){
        int m = m0 + wm * 64 + mi * 16 + g * 4 + r;
        int n = n0 + wn * 64 + ni * 16 + li;
        out[(long)m * 1024 + n] = acc[mi][ni][r] + bfc[n];
      }
}

// ---------------- fused rel-pos attention (v3: j-split + LDS-staged K/V) ----------------
// grid (16 i-tiles, 64 bh), 256 threads; 4 waves j-split one 64-row i-tile.
// r3/r4 plateau diagnosis: K/V fragment loads from global are strided gathers
// (16B @128B stride, 8B @2KB stride -> ~16 transactions/instr); r4 prefetch
// (same transaction count) changed nothing; v2 (4x transactions) was 2.5x worse.
// Fix: stage K[128][64] + V^T[64][128] tiles in LDS per jt via coalesced
// global_load_lds (gemm_core pattern), fragments read from LDS with XOR swizzle.
// LDS 64KB -> 2 blocks/CU (same residency as r3; gain is pure memory-path).
__launch_bounds__(256, 2)
__global__ void attn_kernel(const u16* __restrict__ Qb, const u16* __restrict__ Kb,
                            const u16* __restrict__ Vt, const u16* __restrict__ rpkb,
                            const u16* __restrict__ rpvT, u16* __restrict__ Hid){
  const int S = 1024;
  int bh = blockIdx.y;
  int i0 = blockIdx.x * 64;
  int bb = bh >> 4, hh = bh & 15;
  const u16* Qp = Qb + (long)bh * S * 64;
  const u16* Kp = Kb + (long)bh * S * 64;
  const u16* Vp = Vt + (long)bh * 64 * S;
  int tid = threadIdx.x, w = tid >> 6, lane = tid & 63, g = lane >> 4, li = lane & 15;

  __shared__ __align__(16) char smem[65536];
  u16* klds = (u16*)smem;                // [128 j][64 d], rows XOR-swz (r&7)<<4 bytes
  u16* vlds = (u16*)(smem + 16384);      // [64 d][128 j], rows XOR-swz (d&15)<<4 bytes
  u16* rqb  = (u16*)(smem + 32768);      // [64][128] rq table (bf16)
  u16* bwb  = (u16*)(smem + 49152);      // [64][128] band weights, XOR-swz (i&7)<<4
  float* redL = (float*)smem;            // [4][64] aliases klds after jt loop
  float* redR = redL + 256;
  float* redD = redR + 256;
  float* Ored = (float*)rqb;             // [64][64] f32 alias of rqb after loop

  // Q fragments (B-operand: col=i=li, k=d)
  s16x8 qf[4][2];
  #pragma unroll
  for (int ni = 0; ni < 4; ++ni)
    #pragma unroll
    for (int kh = 0; kh < 2; ++kh)
      qf[ni][kh] = *(const s16x8*)(Qp + (long)(i0 + ni * 16 + li) * 64 + kh * 32 + g * 8);

  { // zero band buffer (16 KB)
    i32x4 z = {0, 0, 0, 0};
    #pragma unroll
    for (int i = 0; i < 4; ++i) ((i32x4*)bwb)[i * 256 + tid] = z;
  }

  // rq[i][t] = Q[i]·rp_k[t]  (wave w covers t-blocks 2w, 2w+1), stored bf16
  #pragma unroll
  for (int tt = 0; tt < 2; ++tt){
    int tb = w * 2 + tt;
    s16x8 pf0 = *(const s16x8*)(rpkb + (tb * 16 + li) * 64 + g * 8);
    s16x8 pf1 = *(const s16x8*)(rpkb + (tb * 16 + li) * 64 + 32 + g * 8);
    #pragma unroll
    for (int ni = 0; ni < 4; ++ni){
      f32x4 r = {0.f, 0.f, 0.f, 0.f};
      r = mfma16(qf[ni][0], pf0, r);
      r = mfma16(qf[ni][1], pf1, r);
      #pragma unroll
      for (int e = 0; e < 4; ++e)
        rqb[(ni * 16 + g * 4 + e) * 128 + tb * 16 + li] = f2bf(r[e]);
    }
  }
  __syncthreads();

  // edge rq values (t=0: all-left clip; t=126: all-right clip) in registers
  float rqL[4], rqR[4];
  #pragma unroll
  for (int ni = 0; ni < 4; ++ni){
    int iloc = ni * 16 + li;
    rqL[ni] = b2f(rqb[iloc * 128]);
    rqR[ni] = b2f(rqb[iloc * 128 + 126]);
  }

  f32x4 oacc[4][4] = {};
  float dacc[4] = {0, 0, 0, 0}, Lac[4] = {0, 0, 0, 0}, Rac[4] = {0, 0, 0, 0};

  for (int jt = 0; jt < 8; ++jt){
    int jb = jt * 128;
    __syncthreads();                     // prior tile fully consumed
    // stage K tile [128][64] (16KB): coalesced 16B/thread x4, source k pre-swizzled
    #pragma unroll
    for (int p2 = 0; p2 < 4; ++p2){
      int idx = p2 * 256 + tid;          // 16B-unit index (8 per 128B row)
      int r = idx >> 3, s8 = idx & 7;
      int kk = (s8 ^ (r & 7)) << 3;
      gld16(Kp + (long)(jb + r) * 64 + kk, (char*)klds + idx * 16);
    }
    // stage V^T tile [64][128] (16KB): source col-bytes pre-swizzled by (d&15)<<4
    #pragma unroll
    for (int p2 = 0; p2 < 4; ++p2){
      int idx = p2 * 256 + tid;          // 16B-unit index (16 per 256B row)
      int d = idx >> 4, c16 = idx & 15;
      int cb = (c16 * 16) ^ ((d & 15) << 4);
      gld16(Vp + (long)d * S + jb + (cb >> 1), (char*)vlds + idx * 16);
    }
    __syncthreads();                     // drains vmcnt (compiler) + all waves see tile

    int jw = w * 32;                     // wave's 32 j-rows within tile
    s16x8 kf[2][2];
    #pragma unroll
    for (int p = 0; p < 2; ++p)
      #pragma unroll
      for (int kh = 0; kh < 2; ++kh){
        int row = jw + p * 16 + li;
        int byt = (row * 128 + (kh * 32 + g * 8) * 2) ^ ((li & 7) << 4);
        kf[p][kh] = *(const s16x8*)((const char*)klds + byt);
      }
    s16x8 vv[4];
    #pragma unroll
    for (int nd = 0; nd < 4; ++nd){
      int d = nd * 16 + li;
      int o1 = (jw * 2 + g * 8) ^ ((li & 15) << 4);
      int o2 = (jw * 2 + g * 8 + 32) ^ ((li & 15) << 4);
      s16x4 vlo = *(const s16x4*)((const char*)vlds + d * 256 + o1);
      s16x4 vhi = *(const s16x4*)((const char*)vlds + d * 256 + o2);
      vv[nd] = cat4(vlo, vhi);
    }
    s16x8 av[4];
    #pragma unroll
    for (int mi = 0; mi < 2; ++mi){
      int js0 = jb + jw + mi * 16;       // global j-base of subtile
      f32x4 sacc[4];
      #pragma unroll
      for (int ni = 0; ni < 4; ++ni){
        f32x4 s0 = {0.f, 0.f, 0.f, 0.f};
        s0 = mfma16(kf[mi][0], qf[ni][0], s0);  // S^T: rows j, cols i
        s0 = mfma16(kf[mi][1], qf[ni][1], s0);
        sacc[ni] = s0;
      }
      if (js0 >= i0 + 126){
        // fast path: whole subtile right-clipped (t=126)
        #pragma unroll
        for (int ni = 0; ni < 4; ++ni)
          #pragma unroll
          for (int r = 0; r < 4; ++r){
            float e = EXP2(sacc[ni][r] + rqR[ni]);
            Rac[ni] += e;
            av[ni][mi * 4 + r] = e2s(e);
          }
      } else if (js0 + 78 <= i0){
        // fast path: whole subtile left-clipped (t=0)
        #pragma unroll
        for (int ni = 0; ni < 4; ++ni)
          #pragma unroll
          for (int r = 0; r < 4; ++r){
            float e = EXP2(sacc[ni][r] + rqL[ni]);
            Lac[ni] += e;
            av[ni][mi * 4 + r] = e2s(e);
          }
      } else {
        // mixed subtile: clamped rq gather (bank-spread), in-band bw write
        #pragma unroll
        for (int ni = 0; ni < 4; ++ni){
          int iloc = ni * 16 + li;
          #pragma unroll
          for (int r = 0; r < 4; ++r){
            int jgl = js0 + g * 4 + r;
            int delta = jgl - (i0 + iloc);
            int dcl = delta < -62 ? -62 : (delta > 62 ? 62 : delta);
            int tg = dcl + 63;                  // in [1,125]
            float rqv = b2f(rqb[iloc * 128 + tg]);
            bool lft = delta < -62, rgt = delta > 62;
            rqv = lft ? rqL[ni] : (rgt ? rqR[ni] : rqv);
            float e = EXP2(sacc[ni][r] + rqv);
            short eb = e2s(e);
            av[ni][mi * 4 + r] = eb;
            if (!lft && !rgt){
              int byt = (iloc * 256 + tg * 2) ^ ((iloc & 7) << 4);
              *(u16*)((char*)bwb + byt) = (u16)eb;
              dacc[ni] += e;
            }
            Lac[ni] += lft ? e : 0.f;
            Rac[ni] += rgt ? e : 0.f;
          }
        }
      }
    }
    // PV: A = exp(S^T) fragments, B = V^T fragments (matching slot k-map)
    #pragma unroll
    for (int nd = 0; nd < 4; ++nd)
      #pragma unroll
      for (int ni = 0; ni < 4; ++ni)
        oacc[ni][nd] = mfma16(av[ni], vv[nd], oacc[ni][nd]);
  }

  __syncthreads();                       // all waves done with klds before red alias
  // butterfly over the 4 lane-groups (j-partials)
  #pragma unroll
  for (int ni = 0; ni < 4; ++ni){
    dacc[ni] += __shfl_xor(dacc[ni], 16); dacc[ni] += __shfl_xor(dacc[ni], 32);
    Lac[ni]  += __shfl_xor(Lac[ni], 16);  Lac[ni]  += __shfl_xor(Lac[ni], 32);
    Rac[ni]  += __shfl_xor(Rac[ni], 16);  Rac[ni]  += __shfl_xor(Rac[ni], 32);
  }
  if (g == 0){
    #pragma unroll
    for (int ni = 0; ni < 4; ++ni){
      redL[w * 64 + ni * 16 + li] = Lac[ni];
      redR[w * 64 + ni * 16 + li] = Rac[ni];
      redD[w * 64 + ni * 16 + li] = dacc[ni];
    }
  }
  __syncthreads();
  if (tid < 64){
    int i = tid;
    float Ls = redL[i] + redL[64 + i] + redL[128 + i] + redL[192 + i];
    float Rs = redR[i] + redR[64 + i] + redR[128 + i] + redR[192 + i];
    float Ds = redD[i] + redD[64 + i] + redD[128 + i] + redD[192 + i] + Ls + Rs;
    *(u16*)((char*)bwb + ((i * 256 + 0)   ^ ((i & 7) << 4))) = f2bf(Ls);  // t=0 tail
    *(u16*)((char*)bwb + ((i * 256 + 252) ^ ((i & 7) << 4))) = f2bf(Rs);  // t=126 tail
    redD[i] = Ds;
  }
  // cross-wave O reduction into Ored (aliases rqb; rq gathers are done)
  for (int ww = 0; ww < 4; ++ww){
    if (w == ww){
      #pragma unroll
      for (int ni = 0; ni < 4; ++ni)
        #pragma unroll
        for (int nd = 0; nd < 4; ++nd)
          #pragma unroll
          for (int r = 0; r < 4; ++r){
            int i = ni * 16 + g * 4 + r, d = nd * 16 + li;
            if (ww == 0) Ored[i * 64 + d] = oacc[ni][nd][r];
            else         Ored[i * 64 + d] += oacc[ni][nd][r];
          }
    }
    __syncthreads();
  }
  // band GEMM: out_bias = bw[64][128] @ rpvT^T ; wave w owns d-block w
  s16x8 rvf[4];
  #pragma unroll
  for (int ksl = 0; ksl < 4; ++ksl)
    rvf[ksl] = *(const s16x8*)(rpvT + (w * 16 + li) * 128 + ksl * 32 + g * 8);
  f32x4 bacc[4];
  #pragma unroll
  for (int mi = 0; mi < 4; ++mi){
    f32x4 a4 = {0.f, 0.f, 0.f, 0.f};
    #pragma unroll
    for (int ksl = 0; ksl < 4; ++ksl){
      int row = mi * 16 + li;
      int byt = (row * 256 + (ksl * 32 + g * 8) * 2) ^ ((row & 7) << 4);
      s16x8 a = *(const s16x8*)((const char*)bwb + byt);
      a4 = mfma16(a, rvf[ksl], a4);
    }
    bacc[mi] = a4;
  }
  // final normalize + write hidden[b][s][h*64+d]
  #pragma unroll
  for (int mi = 0; mi < 4; ++mi)
    #pragma unroll
    for (int r = 0; r < 4; ++r){
      int i = mi * 16 + g * 4 + r;
      float den = redD[i];
      float o = (Ored[i * 64 + w * 16 + li] + bacc[mi][r]) / den;
      Hid[((long)bb * S + i0 + i) * 1024 + hh * 64 + w * 16 + li] = f2bf(o);
    }
}

// ---------------- launch ----------------
extern "C" void kernel_launch(void* const* d_in, const int* in_sizes, int n_in,
                              void* d_out, int out_size, void* d_ws, size_t ws_size,
                              hipStream_t stream){
  const float* query = (const float*)d_in[0];
  const float* key   = (const float*)d_in[1];
  const float* value = (const float*)d_in[2];
  const float* Wq  = (const float*)d_in[3];
  const float* Wk  = (const float*)d_in[4];
  const float* Wv  = (const float*)d_in[5];
  const float* bq  = (const float*)d_in[6];
  const float* bk  = (const float*)d_in[7];
  const float* bv  = (const float*)d_in[8];
  const float* rpk = (const float*)d_in[9];
  const float* rpv = (const float*)d_in[10];
  const float* Wfc = (const float*)d_in[11];
  const float* bfc = (const float*)d_in[12];
  float* out = (float*)d_out;

  u16* Xb   = (u16*)d_ws;                  // [3][4096][1024]
  u16* Wt   = Xb + 3L * 4096 * 1024;       // [3072][1024]
  u16* Wfcb = Wt + 3072L * 1024;           // [1024][1024]
  u16* rpkb = Wfcb + 1024L * 1024;         // [128][64]
  u16* rpvT = rpkb + 128 * 64;             // [64][128]
  u16* Qb   = rpvT + 64 * 128;             // [64][1024][64]
  u16* Kb   = Qb + 64L * 1024 * 64;
  u16* Vb   = Kb + 64L * 1024 * 64;
  u16* Vt   = Vb + 64L * 1024 * 64;        // [64][64][1024]
  u16* Hid  = Vt + 64L * 1024 * 64;        // [4096][1024]

  cast3_kernel<<<2048, 256, 0, stream>>>(query, key, value, Xb);
  cast1_kernel<<<512, 256, 0, stream>>>(Wfc, Wfcb, 1024L * 1024);
  wtrans_kernel<<<768, 256, 0, stream>>>(Wq, Wk, Wv, Wt);
  tables_kernel<<<1, 256, 0, stream>>>(rpk, rpv, rpkb, rpvT);
  gemm_qkv<<<768, 256, 0, stream>>>(Xb, Wt, bq, bk, bv, Qb, Kb, Vb);
  vtrans_kernel<<<1024, 256, 0, stream>>>(Vb, Vt);
  attn_kernel<<<dim3(16, 64), 256, 0, stream>>>(Qb, Kb, Vt, rpkb, rpvT, Hid);
  gemm_fc<<<256, 256, 0, stream>>>(Hid, Wfcb, bfc, out);
}